// Round 8
// baseline (18881.395 us; speedup 1.0000x reference)
//
#include <hip/hip_runtime.h>

typedef unsigned short u16;
typedef __attribute__((ext_vector_type(8))) short bf16x8;
typedef __attribute__((ext_vector_type(4))) float f32x4;

#define B_   2
#define S_   2048
#define HID_ 1024
#define NH_  16
#define HD_  64
#define SCALE_ 0.125f    // 1/sqrt(64)

__device__ __forceinline__ float bf2f(u16 u) {
    union { unsigned int i; float f; } v; v.i = ((unsigned int)u) << 16; return v.f;
}
__device__ __forceinline__ u16 f2bf(float f) {
    union { float f; unsigned int i; } v; v.f = f;
    unsigned int r = v.i + 0x7fffu + ((v.i >> 16) & 1u);   // RNE
    return (u16)(r >> 16);
}
__device__ __forceinline__ bf16x8 ld8(const u16* p) {
    return *reinterpret_cast<const bf16x8*>(p);
}
// scalar load from dual-dtype source (fl=1: bf16-stored, fl=0: fp32-stored)
__device__ __forceinline__ float scal_dyn(const void* base, size_t off, int fl) {
    return fl ? bf2f(((const u16*)base)[off]) : ((const float*)base)[off];
}

// ---------------------------------------------------------------------------
// Per-input dtype detection (kept from R7; robust either way).
// ---------------------------------------------------------------------------
__global__ void detect9(
    const void* X, const void* M,
    const void* W0, const void* W1, const void* W2,
    const void* b0, const void* b1, const void* b2, const void* hwp,
    int* __restrict__ flags)
{
    const int which = blockIdx.x;
    const void* p; int n;
    switch (which) {
        case 0: p = X;  n = 4194304; break;
        case 1: p = M;  n = 8388608; break;
        case 2: p = W0; n = 1048576; break;
        case 3: p = W1; n = 1048576; break;
        case 4: p = W2; n = 1048576; break;
        case 5: p = b0; n = 1024;    break;
        case 6: p = b1; n = 1024;    break;
        case 7: p = b2; n = 1024;    break;
        default: p = hwp; n = 16;    break;
    }
    const int lane = threadIdx.x & 63;
    const int s = n / 2 < 64 ? n / 2 : 64;
    int bf = 0, nzv = 0;
    if (lane < s) {
        const u16 lo = ((const u16*)p)[2 * lane];
        const u16 hi = ((const u16*)p)[2 * lane + 1];
        if ((lo | hi) != 0) {
            nzv = 1;
            const int e = (lo >> 7) & 0xFF;
            bf = (lo != 0 && e >= 100 && e <= 140) ? 1 : 0;
        }
    }
    #pragma unroll
    for (int off = 1; off < 64; off <<= 1) {
        bf  += __shfl_xor(bf, off);
        nzv += __shfl_xor(nzv, off);
    }
    if (lane == 0) flags[which] = (nzv == 0) ? 1 : ((2 * bf >= nzv) ? 1 : 0);
}

// ---------------------------------------------------------------------------
// Stage 1 (pure VALU): Y = X @ W^T + b, LDS-tiled fp32, write (B,NH,S,HD) bf16.
// ---------------------------------------------------------------------------
__global__ __launch_bounds__(256) void qkv_valu(
    const void* __restrict__ X,
    const void* __restrict__ Wq, const void* __restrict__ bq,
    const void* __restrict__ Wk, const void* __restrict__ bk,
    const void* __restrict__ Wv, const void* __restrict__ bv,
    const int* __restrict__ flags,
    u16* __restrict__ Q, u16* __restrict__ K, u16* __restrict__ V)
{
    __shared__ float Xs[64][33];
    __shared__ float Ws[64][33];

    const int which = blockIdx.z;
    const void* W    = which == 0 ? Wq : which == 1 ? Wk : Wv;
    const void* bias = which == 0 ? bq : which == 1 ? bk : bv;
    u16*       Y     = which == 0 ? Q  : which == 1 ? K  : V;

    const int flX = flags[0];
    const int flW = flags[2 + which];
    const int flB = flags[5 + which];

    const int t  = threadIdx.x;
    const int i0 = blockIdx.x * 64;
    const int j0 = blockIdx.y * 64;

    const int sr  = t >> 2;
    const int sc0 = (t & 3) * 8;
    const int il0 = (t >> 4) * 4;
    const int jl0 = (t & 15) * 4;

    float acc[4][4] = {};

    for (int k0 = 0; k0 < HID_; k0 += 32) {
        __syncthreads();
        #pragma unroll
        for (int e = 0; e < 8; e++) {
            Xs[sr][sc0 + e] = scal_dyn(X, (size_t)(i0 + sr) * HID_ + k0 + sc0 + e, flX);
            Ws[sr][sc0 + e] = scal_dyn(W, (size_t)(j0 + sr) * HID_ + k0 + sc0 + e, flW);
        }
        __syncthreads();

        #pragma unroll 8
        for (int kk = 0; kk < 32; kk++) {
            float xa[4], wb[4];
            #pragma unroll
            for (int a = 0; a < 4; a++) xa[a] = Xs[il0 + a][kk];
            #pragma unroll
            for (int c = 0; c < 4; c++) wb[c] = Ws[jl0 + c][kk];
            #pragma unroll
            for (int a = 0; a < 4; a++)
                #pragma unroll
                for (int c = 0; c < 4; c++) acc[a][c] += xa[a] * wb[c];
        }
    }

    #pragma unroll
    for (int a = 0; a < 4; a++) {
        const int i = i0 + il0 + a;
        const int b = i >> 11, s = i & (S_ - 1);
        #pragma unroll
        for (int c = 0; c < 4; c++) {
            const int j = j0 + jl0 + c;
            const int h = j >> 6, d = j & 63;
            Y[(((size_t)(b * NH_ + h) * S_ + s) * HD_) + d] =
                f2bf(acc[a][c] + scal_dyn(bias, j, flB));
        }
    }
}

// ---------------------------------------------------------------------------
// Stage 2 (pure VALU): flash-style attention. Thread t owns q-row (t>>2);
// 4 row-threads split keys/dims into 16-slices. FP32 outputs.
// ---------------------------------------------------------------------------
__global__ __launch_bounds__(256) void attn_valu(
    const u16* __restrict__ Q, const u16* __restrict__ K, const u16* __restrict__ V,
    const void* __restrict__ mask, const void* __restrict__ hw,
    const int* __restrict__ flags,
    float* __restrict__ ctx, float* __restrict__ probs_out)
{
    __shared__ float Qs[64][68];
    __shared__ float Ks[64][68];
    __shared__ float Vs[64][68];
    __shared__ float Ps[64][68];

    const int flM = flags[1];
    const int flH = flags[8];
    const int t   = threadIdx.x;

    const int qb = blockIdx.x;
    const int h  = blockIdx.y;
    const int b  = blockIdx.z;
    const int bh = b * NH_ + h;

    const u16* Qh = Q + (size_t)bh * S_ * HD_;
    const u16* Kh = K + (size_t)bh * S_ * HD_;
    const u16* Vh = V + (size_t)bh * S_ * HD_;
    const size_t moff = (size_t)b * S_ * S_;

    const int q0  = qb * 64;
    const int q_l = t >> 2;
    const int sub = t & 3;
    const int ks0 = sub * 16;

    {   // stage Q rows (bf16 -> fp32), once
        const int r  = t >> 2;
        const int c0 = (t & 3) * 16;
        bf16x8 a0 = ld8(Qh + (size_t)(q0 + r) * HD_ + c0);
        bf16x8 a1 = ld8(Qh + (size_t)(q0 + r) * HD_ + c0 + 8);
        #pragma unroll
        for (int e = 0; e < 8; e++) { Qs[r][c0 + e] = bf2f((u16)a0[e]); Qs[r][c0 + 8 + e] = bf2f((u16)a1[e]); }
    }

    float m_r = -1e30f, l_r = 0.f;
    f32x4 O4[4] = {};

    for (int kt = 0; kt < S_; kt += 64) {
        __syncthreads();

        {   // stage K,V tiles
            const int r  = t >> 2;
            const int c0 = (t & 3) * 16;
            bf16x8 k0 = ld8(Kh + (size_t)(kt + r) * HD_ + c0);
            bf16x8 k1 = ld8(Kh + (size_t)(kt + r) * HD_ + c0 + 8);
            bf16x8 v0 = ld8(Vh + (size_t)(kt + r) * HD_ + c0);
            bf16x8 v1 = ld8(Vh + (size_t)(kt + r) * HD_ + c0 + 8);
            #pragma unroll
            for (int e = 0; e < 8; e++) {
                Ks[r][c0 + e] = bf2f((u16)k0[e]); Ks[r][c0 + 8 + e] = bf2f((u16)k1[e]);
                Vs[r][c0 + e] = bf2f((u16)v0[e]); Vs[r][c0 + 8 + e] = bf2f((u16)v1[e]);
            }
        }
        __syncthreads();

        float sc16[16];
        #pragma unroll
        for (int kk = 0; kk < 16; kk++) sc16[kk] = 0.f;
        #pragma unroll
        for (int d0 = 0; d0 < 64; d0 += 16) {
            f32x4 q4[4];
            #pragma unroll
            for (int e = 0; e < 4; e++) q4[e] = *(const f32x4*)&Qs[q_l][d0 + 4 * e];
            #pragma unroll
            for (int kk = 0; kk < 16; kk++) {
                const f32x4* kr = (const f32x4*)&Ks[ks0 + kk][d0];
                f32x4 a = q4[0] * kr[0] + q4[1] * kr[1] + q4[2] * kr[2] + q4[3] * kr[3];
                sc16[kk] += a[0] + a[1] + a[2] + a[3];
            }
        }
        #pragma unroll
        for (int kk = 0; kk < 16; kk++) {
            const size_t mi = moff + (size_t)(q0 + q_l) * S_ + kt + ks0 + kk;
            sc16[kk] = sc16[kk] * SCALE_ + scal_dyn(mask, mi, flM);
        }

        float mt = sc16[0];
        #pragma unroll
        for (int kk = 1; kk < 16; kk++) mt = fmaxf(mt, sc16[kk]);
        mt = fmaxf(mt, __shfl_xor(mt, 1));
        mt = fmaxf(mt, __shfl_xor(mt, 2));
        const float mn    = fmaxf(m_r, mt);
        const float alpha = __expf(m_r - mn);
        m_r = mn;

        float ps = 0.f;
        #pragma unroll
        for (int kk = 0; kk < 16; kk++) {
            float p = __expf(sc16[kk] - mn);
            Ps[q_l][ks0 + kk] = p;
            ps += p;
        }
        ps += __shfl_xor(ps, 1);
        ps += __shfl_xor(ps, 2);
        l_r = l_r * alpha + ps;
        #pragma unroll
        for (int e = 0; e < 4; e++) O4[e] *= alpha;

        __syncthreads();

        for (int key = 0; key < 64; key++) {
            const float pk = Ps[q_l][key];
            const f32x4* vr = (const f32x4*)&Vs[key][ks0];
            #pragma unroll
            for (int e = 0; e < 4; e++) O4[e] += pk * vr[e];
        }
    }

    const float hwf  = scal_dyn(hw, h, flH);
    const float invl = hwf / l_r;
    #pragma unroll
    for (int e = 0; e < 4; e++)
        #pragma unroll
        for (int i = 0; i < 4; i++) {
            ctx[((size_t)(b * S_ + q0 + q_l)) * HID_ + h * HD_ + ks0 + 4 * e + i] =
                O4[e][i] * invl;
        }

    if (q0 >= 1920) {
        for (int kt = 0; kt < S_; kt += 64) {
            __syncthreads();
            {
                const int r  = t >> 2;
                const int c0 = (t & 3) * 16;
                bf16x8 k0 = ld8(Kh + (size_t)(kt + r) * HD_ + c0);
                bf16x8 k1 = ld8(Kh + (size_t)(kt + r) * HD_ + c0 + 8);
                #pragma unroll
                for (int e = 0; e < 8; e++) { Ks[r][c0 + e] = bf2f((u16)k0[e]); Ks[r][c0 + 8 + e] = bf2f((u16)k1[e]); }
            }
            __syncthreads();

            float sc16[16];
            #pragma unroll
            for (int kk = 0; kk < 16; kk++) sc16[kk] = 0.f;
            #pragma unroll
            for (int d0 = 0; d0 < 64; d0 += 16) {
                f32x4 q4[4];
                #pragma unroll
                for (int e = 0; e < 4; e++) q4[e] = *(const f32x4*)&Qs[q_l][d0 + 4 * e];
                #pragma unroll
                for (int kk = 0; kk < 16; kk++) {
                    const f32x4* kr = (const f32x4*)&Ks[ks0 + kk][d0];
                    f32x4 a = q4[0] * kr[0] + q4[1] * kr[1] + q4[2] * kr[2] + q4[3] * kr[3];
                    sc16[kk] += a[0] + a[1] + a[2] + a[3];
                }
            }
            #pragma unroll
            for (int kk = 0; kk < 16; kk++) {
                const size_t mi = moff + (size_t)(q0 + q_l) * S_ + kt + ks0 + kk;
                float s = sc16[kk] * SCALE_ + scal_dyn(mask, mi, flM);
                float p = __expf(s - m_r) * invl;
                probs_out[((size_t)bh * 128 + (q0 + q_l - 1920)) * S_ + kt + ks0 + kk] = p;
            }
        }
    }
}

// ---------------------------------------------------------------------------
extern "C" void kernel_launch(void* const* d_in, const int* in_sizes, int n_in,
                              void* d_out, int out_size, void* d_ws, size_t ws_size,
                              hipStream_t stream)
{
    const void* X = 0; const void* mask = 0; const void* hw = 0;
    const void* Wm[3] = {0, 0, 0}; const void* bm[3] = {0, 0, 0};
    int wi = 0, bi = 0;
    for (int i = 0; i < n_in; i++) {
        switch (in_sizes[i]) {
            case 4194304: X = d_in[i]; break;
            case 8388608: mask = d_in[i]; break;
            case 1048576: if (wi < 3) Wm[wi++] = d_in[i]; break;
            case 1024:    if (bi < 3) bm[bi++] = d_in[i]; break;
            case 16:      hw = d_in[i]; break;
            default: break;
        }
    }
    if (!X || !mask || wi != 3 || bi != 3 || !hw) {
        X = d_in[0]; mask = d_in[1];
        Wm[0] = d_in[2]; bm[0] = d_in[3];
        Wm[1] = d_in[4]; bm[1] = d_in[5];
        Wm[2] = d_in[6]; bm[2] = d_in[7];
        hw = d_in[8];
    }

    int* flags = (int*)d_ws;
    u16* Q     = (u16*)d_ws + 128;           // +256 B, 16B-aligned
    u16* K     = Q + 4194304ull;
    u16* V     = K + 4194304ull;             // total ws use: 24 MB + 256 B

    float* ctx   = (float*)d_out;                           // fp32 output!
    float* probs = ctx + (size_t)B_ * S_ * HID_;            // fp32 output!

    detect9<<<9, 64, 0, stream>>>(X, mask, Wm[0], Wm[1], Wm[2],
                                  bm[0], bm[1], bm[2], hw, flags);

    dim3 g1(S_ * B_ / 64, HID_ / 64, 3);   // (64,16,3)
    qkv_valu<<<g1, dim3(256), 0, stream>>>(X, Wm[0], bm[0], Wm[1], bm[1], Wm[2], bm[2],
                                           flags, Q, K, V);

    dim3 g2(S_ / 64, NH_, B_);             // (32,16,2)
    attn_valu<<<g2, dim3(256), 0, stream>>>(Q, K, V, mask, hw, flags, ctx, probs);
}

// Round 9
// 875.287 us; speedup vs baseline: 21.5717x; 21.5717x over previous
//
#include <hip/hip_runtime.h>

typedef unsigned short u16;
typedef __attribute__((ext_vector_type(8))) short bf16x8;   // 8 bf16 = 4 VGPRs
typedef __attribute__((ext_vector_type(4))) float f32x4;

#define B_   2
#define S_   2048
#define HID_ 1024
#define NH_  16
#define HD_  64
#define SCALE_ 0.125f    // 1/sqrt(64)

__device__ __forceinline__ float bf2f(u16 u) {
    union { unsigned int i; float f; } v; v.i = ((unsigned int)u) << 16; return v.f;
}
__device__ __forceinline__ u16 f2bf(float f) {
    union { float f; unsigned int i; } v; v.f = f;
    unsigned int r = v.i + 0x7fffu + ((v.i >> 16) & 1u);   // RNE
    return (u16)(r >> 16);
}
__device__ __forceinline__ bf16x8 ld8(const u16* p) {
    return *reinterpret_cast<const bf16x8*>(p);
}
// load 8 fp32, round to bf16 fragment
__device__ __forceinline__ bf16x8 ld8_f32(const float* p) {
    f32x4 a = *(const f32x4*)p;
    f32x4 b = *(const f32x4*)(p + 4);
    bf16x8 r;
    #pragma unroll
    for (int e = 0; e < 4; e++) { r[e] = (short)f2bf(a[e]); r[4 + e] = (short)f2bf(b[e]); }
    return r;
}

// ---------------------------------------------------------------------------
// Stage 1: Y = X @ W^T + b (MFMA, fp32 inputs converted in-flight),
// write as (B,NH,S,HD) bf16 workspace.
// Block = 4 waves; tile 64(M) x 64(N); wave = 16 rows.
// ---------------------------------------------------------------------------
__global__ __launch_bounds__(256) void qkv_proj(
    const float* __restrict__ X,
    const float* __restrict__ Wq, const float* __restrict__ bq,
    const float* __restrict__ Wk, const float* __restrict__ bk,
    const float* __restrict__ Wv, const float* __restrict__ bv,
    u16* __restrict__ Q, u16* __restrict__ K, u16* __restrict__ V)
{
    const int which = blockIdx.z;
    const float* W    = which == 0 ? Wq : which == 1 ? Wk : Wv;
    const float* bias = which == 0 ? bq : which == 1 ? bk : bv;
    u16*         Y    = which == 0 ? Q  : which == 1 ? K  : V;

    const int tid  = threadIdx.x;
    const int wave = tid >> 6;
    const int lane = tid & 63;
    const int l16  = lane & 15;
    const int quad = lane >> 4;

    const int i0 = blockIdx.x * 64 + wave * 16;   // row base (this wave)
    const int j0 = blockIdx.y * 64;               // col base (block)

    f32x4 acc[4] = {};

    const float* xrow = X + (size_t)(i0 + l16) * HID_ + quad * 8;
    for (int k0 = 0; k0 < HID_; k0 += 32) {
        bf16x8 a = ld8_f32(xrow + k0);
        #pragma unroll
        for (int nb = 0; nb < 4; nb++) {
            bf16x8 bf = ld8_f32(W + (size_t)(j0 + nb * 16 + l16) * HID_ + k0 + quad * 8);
            acc[nb] = __builtin_amdgcn_mfma_f32_16x16x32_bf16(a, bf, acc[nb], 0, 0, 0);
        }
    }

    #pragma unroll
    for (int nb = 0; nb < 4; nb++) {
        const int j = j0 + nb * 16 + l16;
        const float bv_ = bias[j];
        const int h = j >> 6, d = j & 63;
        #pragma unroll
        for (int r = 0; r < 4; r++) {
            const int i = i0 + quad * 4 + r;          // C layout: row = quad*4+reg
            const int b = i >> 11, s = i & (S_ - 1);
            Y[(((size_t)(b * NH_ + h) * S_ + s) * HD_) + d] = f2bf(acc[nb][r] + bv_);
        }
    }
}

// ---------------------------------------------------------------------------
// Stage 2: attention. Block = 4 waves, one (b,h), 64 q rows; wave = 16 rows.
// MFMA QK^T -> register online softmax (quad shuffle stats) -> P via LDS
// (C->A layout) -> MFMA PV against V^T tile in LDS. FP32 mask in, FP32 out.
// ---------------------------------------------------------------------------
#define BN_  64
#define LDP_ 72   // padded LDS row stride (bf16 elems): 144 B, 16B-aligned

__global__ __launch_bounds__(256) void attn(
    const u16* __restrict__ Q, const u16* __restrict__ K, const u16* __restrict__ V,
    const float* __restrict__ mask, const float* __restrict__ hw,
    float* __restrict__ ctx, float* __restrict__ probs_out)
{
    __shared__ __align__(16) u16 Vt[HD_][LDP_];     // V^T tile: [hd][key]
    __shared__ __align__(16) u16 Pl[4][16][LDP_];   // per-wave P tile: [m][key]

    const int tid  = threadIdx.x;
    const int wave = tid >> 6;
    const int lane = tid & 63;
    const int l16  = lane & 15;
    const int quad = lane >> 4;

    const int qb = blockIdx.x;          // 0..31
    const int h  = blockIdx.y;
    const int b  = blockIdx.z;
    const int bh = b * NH_ + h;

    const u16* Qh = Q + (size_t)bh * S_ * HD_;
    const u16* Kh = K + (size_t)bh * S_ * HD_;
    const u16* Vh = V + (size_t)bh * S_ * HD_;
    const float* Mb = mask + (size_t)b * S_ * S_;

    const int q0 = qb * 64 + wave * 16;

    // Q fragments, resident for the whole kernel
    bf16x8 qf0 = ld8(Qh + (size_t)(q0 + l16) * HD_ + quad * 8);
    bf16x8 qf1 = ld8(Qh + (size_t)(q0 + l16) * HD_ + 32 + quad * 8);

    f32x4 oacc[4] = {};
    float m_i[4], l_i[4];
    #pragma unroll
    for (int r = 0; r < 4; r++) { m_i[r] = -1e30f; l_i[r] = 0.f; }

    for (int kt = 0; kt < S_; kt += BN_) {
        __syncthreads();   // prior iter's Vt/Pl reads complete before overwrite

        // --- stage V tile transposed: Vt[d][key] ---
        {
            const int r  = tid >> 2;            // key within tile 0..63
            const int d0 = (tid & 3) * 16;
            bf16x8 v0 = ld8(Vh + (size_t)(kt + r) * HD_ + d0);
            bf16x8 v1 = ld8(Vh + (size_t)(kt + r) * HD_ + d0 + 8);
            #pragma unroll
            for (int e = 0; e < 8; e++) Vt[d0 + e][r]     = (u16)v0[e];
            #pragma unroll
            for (int e = 0; e < 8; e++) Vt[d0 + 8 + e][r] = (u16)v1[e];
        }

        // --- S = Q K^T * scale + mask ---
        f32x4 sacc[4] = {};
        #pragma unroll
        for (int nb = 0; nb < 4; nb++) {
            const u16* krow = Kh + (size_t)(kt + nb * 16 + l16) * HD_ + quad * 8;
            bf16x8 k0 = ld8(krow);
            bf16x8 k1 = ld8(krow + 32);
            sacc[nb] = __builtin_amdgcn_mfma_f32_16x16x32_bf16(qf0, k0, sacc[nb], 0, 0, 0);
            sacc[nb] = __builtin_amdgcn_mfma_f32_16x16x32_bf16(qf1, k1, sacc[nb], 0, 0, 0);
        }
        float sc[4][4];
        #pragma unroll
        for (int nb = 0; nb < 4; nb++)
            #pragma unroll
            for (int r = 0; r < 4; r++) {
                const int qrow = q0 + quad * 4 + r;
                const int key  = kt + nb * 16 + l16;
                sc[nb][r] = sacc[nb][r] * SCALE_ + Mb[(size_t)qrow * S_ + key];
            }

        // --- online softmax (row stats across quad's 16 lanes) ---
        float mt[4], rs[4];
        #pragma unroll
        for (int r = 0; r < 4; r++) {
            float m = fmaxf(fmaxf(sc[0][r], sc[1][r]), fmaxf(sc[2][r], sc[3][r]));
            #pragma unroll
            for (int off = 1; off < 16; off <<= 1) m = fmaxf(m, __shfl_xor(m, off));
            mt[r] = fmaxf(m_i[r], m);
        }
        float alpha[4];
        #pragma unroll
        for (int r = 0; r < 4; r++) { alpha[r] = __expf(m_i[r] - mt[r]); m_i[r] = mt[r]; rs[r] = 0.f; }

        u16 pb[4][4];
        #pragma unroll
        for (int nb = 0; nb < 4; nb++)
            #pragma unroll
            for (int r = 0; r < 4; r++) {
                float p = __expf(sc[nb][r] - m_i[r]);
                rs[r] += p;
                pb[nb][r] = f2bf(p);
            }
        #pragma unroll
        for (int r = 0; r < 4; r++) {
            float s = rs[r];
            #pragma unroll
            for (int off = 1; off < 16; off <<= 1) s += __shfl_xor(s, off);
            l_i[r] = l_i[r] * alpha[r] + s;
        }
        #pragma unroll
        for (int db = 0; db < 4; db++)
            #pragma unroll
            for (int r = 0; r < 4; r++) oacc[db][r] *= alpha[r];

        // --- P to LDS (C layout -> [m][key] memory) ---
        #pragma unroll
        for (int nb = 0; nb < 4; nb++)
            #pragma unroll
            for (int r = 0; r < 4; r++)
                Pl[wave][quad * 4 + r][nb * 16 + l16] = pb[nb][r];

        __syncthreads();   // Vt + Pl visible

        // --- O += P @ V ---
        #pragma unroll
        for (int kb = 0; kb < 2; kb++) {
            bf16x8 pf = ld8(&Pl[wave][l16][kb * 32 + quad * 8]);
            #pragma unroll
            for (int db = 0; db < 4; db++) {
                bf16x8 vf = ld8(&Vt[db * 16 + l16][kb * 32 + quad * 8]);
                oacc[db] = __builtin_amdgcn_mfma_f32_16x16x32_bf16(pf, vf, oacc[db], 0, 0, 0);
            }
        }
    }

    // --- epilogue: ctx = (O / l) * head_weight (fp32 out) ---
    const float hwf = hw[h];
    float invl[4];
    #pragma unroll
    for (int r = 0; r < 4; r++) invl[r] = hwf / l_i[r];

    #pragma unroll
    for (int db = 0; db < 4; db++)
        #pragma unroll
        for (int r = 0; r < 4; r++) {
            const int qrow = q0 + quad * 4 + r;
            ctx[((size_t)(b * S_ + qrow)) * HID_ + h * HD_ + db * 16 + l16] =
                oacc[db][r] * invl[r];
        }

    // --- probs output for last CHUNK rows: second QK^T pass (fp32 out) ---
    if (qb * 64 >= 1920) {
        for (int kt = 0; kt < S_; kt += BN_) {
            f32x4 sacc[4] = {};
            #pragma unroll
            for (int nb = 0; nb < 4; nb++) {
                const u16* krow = Kh + (size_t)(kt + nb * 16 + l16) * HD_ + quad * 8;
                bf16x8 k0 = ld8(krow);
                bf16x8 k1 = ld8(krow + 32);
                sacc[nb] = __builtin_amdgcn_mfma_f32_16x16x32_bf16(qf0, k0, sacc[nb], 0, 0, 0);
                sacc[nb] = __builtin_amdgcn_mfma_f32_16x16x32_bf16(qf1, k1, sacc[nb], 0, 0, 0);
            }
            #pragma unroll
            for (int nb = 0; nb < 4; nb++)
                #pragma unroll
                for (int r = 0; r < 4; r++) {
                    const int qrow = q0 + quad * 4 + r;
                    const int key  = kt + nb * 16 + l16;
                    float s = sacc[nb][r] * SCALE_ + Mb[(size_t)qrow * S_ + key];
                    float p = __expf(s - m_i[r]) * invl[r];
                    probs_out[((size_t)bh * 128 + (qrow - 1920)) * S_ + key] = p;
                }
        }
    }
}

// ---------------------------------------------------------------------------
extern "C" void kernel_launch(void* const* d_in, const int* in_sizes, int n_in,
                              void* d_out, int out_size, void* d_ws, size_t ws_size,
                              hipStream_t stream)
{
    // Map inputs by size class (robust to ordering); fallback to dict order.
    const void* X = 0; const void* mask = 0; const void* hw = 0;
    const void* Wm[3] = {0, 0, 0}; const void* bm[3] = {0, 0, 0};
    int wi = 0, bi = 0;
    for (int i = 0; i < n_in; i++) {
        switch (in_sizes[i]) {
            case 4194304: X = d_in[i]; break;
            case 8388608: mask = d_in[i]; break;
            case 1048576: if (wi < 3) Wm[wi++] = d_in[i]; break;
            case 1024:    if (bi < 3) bm[bi++] = d_in[i]; break;
            case 16:      hw = d_in[i]; break;
            default: break;
        }
    }
    if (!X || !mask || wi != 3 || bi != 3 || !hw) {
        X = d_in[0]; mask = d_in[1];
        Wm[0] = d_in[2]; bm[0] = d_in[3];
        Wm[1] = d_in[4]; bm[1] = d_in[5];
        Wm[2] = d_in[6]; bm[2] = d_in[7];
        hw = d_in[8];
    }

    u16* Q = (u16*)d_ws;
    u16* K = Q + 4194304ull;
    u16* V = K + 4194304ull;                 // 24 MB bf16 workspace

    float* ctx   = (float*)d_out;
    float* probs = ctx + (size_t)B_ * S_ * HID_;

    dim3 g1(S_ * B_ / 64, HID_ / 64, 3);   // (64,16,3)
    qkv_proj<<<g1, dim3(256), 0, stream>>>(
        (const float*)X,
        (const float*)Wm[0], (const float*)bm[0],
        (const float*)Wm[1], (const float*)bm[1],
        (const float*)Wm[2], (const float*)bm[2],
        Q, K, V);

    dim3 g2(S_ / 64, NH_, B_);             // (32,16,2)
    attn<<<g2, dim3(256), 0, stream>>>(Q, K, V, (const float*)mask, (const float*)hw,
                                       ctx, probs);
}

// Round 10
// 422.562 us; speedup vs baseline: 44.6832x; 2.0714x over previous
//
#include <hip/hip_runtime.h>

typedef unsigned short u16;
typedef __attribute__((ext_vector_type(8))) short bf16x8;   // 8 bf16 = 4 VGPRs
typedef __attribute__((ext_vector_type(4))) float f32x4;

#define B_   2
#define S_   2048
#define HID_ 1024
#define NH_  16
#define HD_  64
#define SCALE_ 0.125f    // 1/sqrt(64)

__device__ __forceinline__ float bf2f(u16 u) {
    union { unsigned int i; float f; } v; v.i = ((unsigned int)u) << 16; return v.f;
}
__device__ __forceinline__ u16 f2bf(float f) {
    union { float f; unsigned int i; } v; v.f = f;
    unsigned int r = v.i + 0x7fffu + ((v.i >> 16) & 1u);   // RNE
    return (u16)(r >> 16);
}
__device__ __forceinline__ bf16x8 ld8(const u16* p) {
    return *reinterpret_cast<const bf16x8*>(p);
}

// ---------------------------------------------------------------------------
// Stage 0a: fp32 -> bf16 arena for X (4M elems) and Wq|Wk|Wv (3x1M elems).
// One thread = 8 elems. Grid 3584 x 256.
// ---------------------------------------------------------------------------
__global__ __launch_bounds__(256) void convert_bf16(
    const float* __restrict__ X, const float* __restrict__ W0,
    const float* __restrict__ W1, const float* __restrict__ W2,
    u16* __restrict__ Xb, u16* __restrict__ Wb)
{
    const size_t s = (size_t)blockIdx.x * 256 + threadIdx.x;
    const float* src; u16* dst; size_t off;
    if (s < 524288) { src = X; dst = Xb; off = s * 8; }
    else {
        const size_t t = s - 524288;
        const int w = (int)(t >> 17);          // 131072 slots per W
        off = (t & 131071) * 8;
        src = w == 0 ? W0 : w == 1 ? W1 : W2;
        dst = Wb + (size_t)w * 1048576;
    }
    f32x4 a = *(const f32x4*)(src + off);
    f32x4 b = *(const f32x4*)(src + off + 4);
    bf16x8 r;
    #pragma unroll
    for (int e = 0; e < 4; e++) { r[e] = (short)f2bf(a[e]); r[4 + e] = (short)f2bf(b[e]); }
    *(bf16x8*)(dst + off) = r;
}

// ---------------------------------------------------------------------------
// Stage 0b: mask scan — flag=1 iff any mask value is nonzero (ignoring -0.0).
// 8.4M floats, 8 per thread, grid 4096 x 256.
// ---------------------------------------------------------------------------
__global__ __launch_bounds__(256) void mask_scan(
    const unsigned* __restrict__ m, unsigned* __restrict__ flag)
{
    const size_t i = ((size_t)blockIdx.x * 256 + threadIdx.x) * 8;
    const uint4* p = (const uint4*)(m + i);
    uint4 a = p[0], b = p[1];
    const unsigned M = 0x7fffffffu;
    unsigned v = (a.x & M) | (a.y & M) | (a.z & M) | (a.w & M)
               | (b.x & M) | (b.y & M) | (b.z & M) | (b.w & M);
    if (v) atomicOr(flag, 1u);
}

// ---------------------------------------------------------------------------
// Stage 1: Y = Xb @ Wb^T + bias, 128x128 tile, 4 waves (2x2), 4x4 MFMA/wave.
// LDS-staged (m93 pattern). Writes bf16 (B,NH,S,HD) workspace.
// ---------------------------------------------------------------------------
#define BK_ 32

__global__ __launch_bounds__(256) void qkv_mfma(
    const u16* __restrict__ Xb, const u16* __restrict__ Wb,
    const float* __restrict__ bq, const float* __restrict__ bk,
    const float* __restrict__ bv,
    u16* __restrict__ Q, u16* __restrict__ K, u16* __restrict__ V)
{
    __shared__ __align__(16) u16 As[128][BK_];   // 8 KB
    __shared__ __align__(16) u16 Bs[128][BK_];   // 8 KB

    const int tid  = threadIdx.x;
    const int wave = tid >> 6;
    const int lane = tid & 63;
    const int l16  = lane & 15;
    const int quad = lane >> 4;
    const int wr   = wave >> 1, wc = wave & 1;

    const int i0 = blockIdx.x * 128;    // row base (32 blocks)
    const int j0 = blockIdx.y * 128;    // col base (24 blocks; within one matrix)

    const int srow = tid >> 2;          // staging row 0..63 (+64 second round)
    const int skc  = (tid & 3) * 8;     // staging k-col

    f32x4 acc[4][4] = {};

    for (int k0 = 0; k0 < HID_; k0 += BK_) {
        __syncthreads();
        #pragma unroll
        for (int q = 0; q < 2; q++) {
            const int row = q * 64 + srow;
            *(bf16x8*)&As[row][skc] = ld8(Xb + (size_t)(i0 + row) * HID_ + k0 + skc);
            *(bf16x8*)&Bs[row][skc] = ld8(Wb + (size_t)(j0 + row) * HID_ + k0 + skc);
        }
        __syncthreads();

        bf16x8 af[4], bf[4];
        #pragma unroll
        for (int mt = 0; mt < 4; mt++) af[mt] = ld8(&As[wr * 64 + mt * 16 + l16][quad * 8]);
        #pragma unroll
        for (int nt = 0; nt < 4; nt++) bf[nt] = ld8(&Bs[wc * 64 + nt * 16 + l16][quad * 8]);
        #pragma unroll
        for (int mt = 0; mt < 4; mt++)
            #pragma unroll
            for (int nt = 0; nt < 4; nt++)
                acc[mt][nt] = __builtin_amdgcn_mfma_f32_16x16x32_bf16(af[mt], bf[nt], acc[mt][nt], 0, 0, 0);
    }

    const int which = j0 >> 10;                     // block-uniform
    const float* bias = which == 0 ? bq : which == 1 ? bk : bv;
    u16* Y            = which == 0 ? Q  : which == 1 ? K  : V;

    #pragma unroll
    for (int nt = 0; nt < 4; nt++) {
        const int j  = j0 + wc * 64 + nt * 16 + l16;
        const int jj = j & 1023;
        const float bv_ = bias[jj];
        const int h = jj >> 6, d = jj & 63;
        #pragma unroll
        for (int mt = 0; mt < 4; mt++)
            #pragma unroll
            for (int r = 0; r < 4; r++) {
                const int i = i0 + wr * 64 + mt * 16 + quad * 4 + r;   // C: row=quad*4+reg
                const int b = i >> 11, s = i & (S_ - 1);
                Y[(((size_t)(b * NH_ + h) * S_ + s) * HD_) + d] = f2bf(acc[mt][nt][r] + bv_);
            }
    }
}

// ---------------------------------------------------------------------------
// Stage 2: attention (R9 structure + mask fast path). Block = 4 waves, one
// (b,h), 64 q rows; wave = 16 rows. FP32 mask/out.
// ---------------------------------------------------------------------------
#define BN_  64
#define LDP_ 72   // padded LDS row stride (bf16 elems): 144 B, 16B-aligned

__global__ __launch_bounds__(256) void attn(
    const u16* __restrict__ Q, const u16* __restrict__ K, const u16* __restrict__ V,
    const float* __restrict__ mask, const float* __restrict__ hw,
    const unsigned* __restrict__ mflag,
    float* __restrict__ ctx, float* __restrict__ probs_out)
{
    __shared__ __align__(16) u16 Vt[HD_][LDP_];     // V^T tile: [hd][key]
    __shared__ __align__(16) u16 Pl[4][16][LDP_];   // per-wave P tile: [m][key]

    const int usemask = (mflag[0] != 0);

    const int tid  = threadIdx.x;
    const int wave = tid >> 6;
    const int lane = tid & 63;
    const int l16  = lane & 15;
    const int quad = lane >> 4;

    const int qb = blockIdx.x;          // 0..31
    const int h  = blockIdx.y;
    const int b  = blockIdx.z;
    const int bh = b * NH_ + h;

    const u16* Qh = Q + (size_t)bh * S_ * HD_;
    const u16* Kh = K + (size_t)bh * S_ * HD_;
    const u16* Vh = V + (size_t)bh * S_ * HD_;
    const float* Mb = mask + (size_t)b * S_ * S_;

    const int q0 = qb * 64 + wave * 16;

    bf16x8 qf0 = ld8(Qh + (size_t)(q0 + l16) * HD_ + quad * 8);
    bf16x8 qf1 = ld8(Qh + (size_t)(q0 + l16) * HD_ + 32 + quad * 8);

    f32x4 oacc[4] = {};
    float m_i[4], l_i[4];
    #pragma unroll
    for (int r = 0; r < 4; r++) { m_i[r] = -1e30f; l_i[r] = 0.f; }

    for (int kt = 0; kt < S_; kt += BN_) {
        __syncthreads();

        {   // stage V^T
            const int r  = tid >> 2;
            const int d0 = (tid & 3) * 16;
            bf16x8 v0 = ld8(Vh + (size_t)(kt + r) * HD_ + d0);
            bf16x8 v1 = ld8(Vh + (size_t)(kt + r) * HD_ + d0 + 8);
            #pragma unroll
            for (int e = 0; e < 8; e++) Vt[d0 + e][r]     = (u16)v0[e];
            #pragma unroll
            for (int e = 0; e < 8; e++) Vt[d0 + 8 + e][r] = (u16)v1[e];
        }

        // --- S = Q K^T * scale (+ mask) ---
        f32x4 sacc[4] = {};
        #pragma unroll
        for (int nb = 0; nb < 4; nb++) {
            const u16* krow = Kh + (size_t)(kt + nb * 16 + l16) * HD_ + quad * 8;
            bf16x8 k0 = ld8(krow);
            bf16x8 k1 = ld8(krow + 32);
            sacc[nb] = __builtin_amdgcn_mfma_f32_16x16x32_bf16(qf0, k0, sacc[nb], 0, 0, 0);
            sacc[nb] = __builtin_amdgcn_mfma_f32_16x16x32_bf16(qf1, k1, sacc[nb], 0, 0, 0);
        }
        float sc[4][4];
        if (usemask) {
            #pragma unroll
            for (int nb = 0; nb < 4; nb++)
                #pragma unroll
                for (int r = 0; r < 4; r++) {
                    const int qrow = q0 + quad * 4 + r;
                    const int key  = kt + nb * 16 + l16;
                    sc[nb][r] = sacc[nb][r] * SCALE_ + Mb[(size_t)qrow * S_ + key];
                }
        } else {
            #pragma unroll
            for (int nb = 0; nb < 4; nb++)
                #pragma unroll
                for (int r = 0; r < 4; r++) sc[nb][r] = sacc[nb][r] * SCALE_;
        }

        // --- online softmax ---
        float mt[4], rs[4];
        #pragma unroll
        for (int r = 0; r < 4; r++) {
            float m = fmaxf(fmaxf(sc[0][r], sc[1][r]), fmaxf(sc[2][r], sc[3][r]));
            #pragma unroll
            for (int off = 1; off < 16; off <<= 1) m = fmaxf(m, __shfl_xor(m, off));
            mt[r] = fmaxf(m_i[r], m);
        }
        float alpha[4];
        #pragma unroll
        for (int r = 0; r < 4; r++) { alpha[r] = __expf(m_i[r] - mt[r]); m_i[r] = mt[r]; rs[r] = 0.f; }

        u16 pb[4][4];
        #pragma unroll
        for (int nb = 0; nb < 4; nb++)
            #pragma unroll
            for (int r = 0; r < 4; r++) {
                float p = __expf(sc[nb][r] - m_i[r]);
                rs[r] += p;
                pb[nb][r] = f2bf(p);
            }
        #pragma unroll
        for (int r = 0; r < 4; r++) {
            float s = rs[r];
            #pragma unroll
            for (int off = 1; off < 16; off <<= 1) s += __shfl_xor(s, off);
            l_i[r] = l_i[r] * alpha[r] + s;
        }
        #pragma unroll
        for (int db = 0; db < 4; db++)
            #pragma unroll
            for (int r = 0; r < 4; r++) oacc[db][r] *= alpha[r];

        // --- P to LDS (C -> [m][key]) ---
        #pragma unroll
        for (int nb = 0; nb < 4; nb++)
            #pragma unroll
            for (int r = 0; r < 4; r++)
                Pl[wave][quad * 4 + r][nb * 16 + l16] = pb[nb][r];

        __syncthreads();

        // --- O += P @ V ---
        #pragma unroll
        for (int kb = 0; kb < 2; kb++) {
            bf16x8 pf = ld8(&Pl[wave][l16][kb * 32 + quad * 8]);
            #pragma unroll
            for (int db = 0; db < 4; db++) {
                bf16x8 vf = ld8(&Vt[db * 16 + l16][kb * 32 + quad * 8]);
                oacc[db] = __builtin_amdgcn_mfma_f32_16x16x32_bf16(pf, vf, oacc[db], 0, 0, 0);
            }
        }
    }

    // --- epilogue ---
    const float hwf = hw[h];
    float invl[4];
    #pragma unroll
    for (int r = 0; r < 4; r++) invl[r] = hwf / l_i[r];

    #pragma unroll
    for (int db = 0; db < 4; db++)
        #pragma unroll
        for (int r = 0; r < 4; r++) {
            const int qrow = q0 + quad * 4 + r;
            ctx[((size_t)(b * S_ + qrow)) * HID_ + h * HD_ + db * 16 + l16] =
                oacc[db][r] * invl[r];
        }

    // --- probs for last CHUNK rows ---
    if (qb * 64 >= 1920) {
        for (int kt = 0; kt < S_; kt += BN_) {
            f32x4 sacc[4] = {};
            #pragma unroll
            for (int nb = 0; nb < 4; nb++) {
                const u16* krow = Kh + (size_t)(kt + nb * 16 + l16) * HD_ + quad * 8;
                bf16x8 k0 = ld8(krow);
                bf16x8 k1 = ld8(krow + 32);
                sacc[nb] = __builtin_amdgcn_mfma_f32_16x16x32_bf16(qf0, k0, sacc[nb], 0, 0, 0);
                sacc[nb] = __builtin_amdgcn_mfma_f32_16x16x32_bf16(qf1, k1, sacc[nb], 0, 0, 0);
            }
            #pragma unroll
            for (int nb = 0; nb < 4; nb++)
                #pragma unroll
                for (int r = 0; r < 4; r++) {
                    const int qrow = q0 + quad * 4 + r;
                    const int key  = kt + nb * 16 + l16;
                    float s = sacc[nb][r] * SCALE_;
                    if (usemask) s += Mb[(size_t)qrow * S_ + key];
                    float p = __expf(s - m_i[r]) * invl[r];
                    probs_out[((size_t)bh * 128 + (qrow - 1920)) * S_ + key] = p;
                }
        }
    }
}

// ---------------------------------------------------------------------------
extern "C" void kernel_launch(void* const* d_in, const int* in_sizes, int n_in,
                              void* d_out, int out_size, void* d_ws, size_t ws_size,
                              hipStream_t stream)
{
    const void* X = 0; const void* mask = 0; const void* hw = 0;
    const void* Wm[3] = {0, 0, 0}; const void* bm[3] = {0, 0, 0};
    int wi = 0, bi = 0;
    for (int i = 0; i < n_in; i++) {
        switch (in_sizes[i]) {
            case 4194304: X = d_in[i]; break;
            case 8388608: mask = d_in[i]; break;
            case 1048576: if (wi < 3) Wm[wi++] = d_in[i]; break;
            case 1024:    if (bi < 3) bm[bi++] = d_in[i]; break;
            case 16:      hw = d_in[i]; break;
            default: break;
        }
    }
    if (!X || !mask || wi != 3 || bi != 3 || !hw) {
        X = d_in[0]; mask = d_in[1];
        Wm[0] = d_in[2]; bm[0] = d_in[3];
        Wm[1] = d_in[4]; bm[1] = d_in[5];
        Wm[2] = d_in[6]; bm[2] = d_in[7];
        hw = d_in[8];
    }

    u16* Q  = (u16*)d_ws;                    // 8 MB
    u16* Kw = Q + 4194304ull;                // 8 MB
    u16* Vw = Kw + 4194304ull;               // 8 MB
    u16* Xb = Vw + 4194304ull;               // 8 MB
    u16* Wb = Xb + 4194304ull;               // 6 MB
    unsigned* flag = (unsigned*)(Wb + 3145728ull);   // 4 B @ 38 MB

    float* ctx   = (float*)d_out;
    float* probs = ctx + (size_t)B_ * S_ * HID_;

    hipMemsetAsync(flag, 0, 4, stream);
    mask_scan<<<4096, 256, 0, stream>>>((const unsigned*)mask, flag);
    convert_bf16<<<3584, 256, 0, stream>>>(
        (const float*)X, (const float*)Wm[0], (const float*)Wm[1], (const float*)Wm[2],
        Xb, Wb);

    qkv_mfma<<<dim3(32, 24), dim3(256), 0, stream>>>(
        Xb, Wb, (const float*)bm[0], (const float*)bm[1], (const float*)bm[2],
        Q, Kw, Vw);

    attn<<<dim3(32, 16, 2), dim3(256), 0, stream>>>(
        Q, Kw, Vw, (const float*)mask, (const float*)hw, flag, ctx, probs);
}